// Round 1
// baseline (1529.441 us; speedup 1.0000x reference)
//
#include <hip/hip_runtime.h>
#include <hip/hip_bf16.h>

// GCN layer: out = relu( dis[n] * ( hs[n] + sum_{e: col=n} w[e]*hs[row[e]] ) + bias )
// where hs = (x@W) * dis[n],  dis = rsqrt(deg),  deg[n] = 1 + sum_{e: col=n} w[e].
// This is algebraically identical to PyG GCNConv with self-loops + sym-norm + ReLU.

#define IN_C 128
#define HID_C 128
#define GEMM_ROWS 8

__global__ __launch_bounds__(256) void k_init_deg(float* deg, int N) {
    int i = blockIdx.x * 256 + threadIdx.x;
    if (i < N) deg[i] = 1.0f;   // self-loop weight 1
}

__global__ __launch_bounds__(256) void k_edge_deg(const int* col, const float* w,
                                                  float* deg, int E) {
    int e = blockIdx.x * 256 + threadIdx.x;
    if (e < E) atomicAdd(&deg[col[e]], w[e]);
}

// hs[n][c] = rsqrt(deg[n]) * sum_k x[n][k] * W[k][c]
// W staged in LDS (64 KB), x tile (8 rows) staged in LDS. Grid-stride over row tiles.
__global__ __launch_bounds__(256) void k_gemm_hs(const float* __restrict__ x,
                                                 const float* __restrict__ W,
                                                 const float* __restrict__ deg,
                                                 float* __restrict__ hs, int N) {
    __shared__ float Ws[IN_C * HID_C];        // 64 KB
    __shared__ float xs[GEMM_ROWS][IN_C];     // 4 KB

    const int t = threadIdx.x;
    // stage W: 16384 floats as float4
    for (int i = t; i < IN_C * HID_C / 4; i += 256)
        ((float4*)Ws)[i] = ((const float4*)W)[i];
    __syncthreads();

    const int r  = t >> 5;          // 0..7  (row within tile)
    const int c0 = (t & 31) * 4;    // 0..124 (4 contiguous output cols)

    for (int base = blockIdx.x * GEMM_ROWS; base < N; base += gridDim.x * GEMM_ROWS) {
        int nrows = min(GEMM_ROWS, N - base);
        for (int i = t; i < nrows * (IN_C / 4); i += 256)
            ((float4*)xs)[i] = ((const float4*)(x + (size_t)base * IN_C))[i];
        __syncthreads();

        if (r < nrows) {
            float a0 = 0.f, a1 = 0.f, a2 = 0.f, a3 = 0.f;
            #pragma unroll 8
            for (int k = 0; k < IN_C; ++k) {
                float a = xs[r][k];
                float4 wv = *(const float4*)&Ws[k * HID_C + c0];
                a0 = fmaf(a, wv.x, a0);
                a1 = fmaf(a, wv.y, a1);
                a2 = fmaf(a, wv.z, a2);
                a3 = fmaf(a, wv.w, a3);
            }
            float dis = rsqrtf(deg[base + r]);   // deg >= 1 always
            float4 o = {a0 * dis, a1 * dis, a2 * dis, a3 * dis};
            *(float4*)&hs[(size_t)(base + r) * HID_C + c0] = o;
        }
        __syncthreads();
    }
}

// Per edge: acc[col] += w * hs[row]  (32 lanes/edge, float4 per lane, 4 atomics)
__global__ __launch_bounds__(256) void k_scatter(const int* __restrict__ row,
                                                 const int* __restrict__ col,
                                                 const float* __restrict__ w,
                                                 const float* __restrict__ hs,
                                                 float* __restrict__ acc, int E) {
    int gid = blockIdx.x * 256 + threadIdx.x;
    int e = gid >> 5;
    int l = gid & 31;            // lane-group index: 32 lanes x float4 = 128 ch
    if (e >= E) return;
    int r = row[e];
    int c = col[e];
    float wt = w[e];
    float4 v = ((const float4*)(hs + (size_t)r * HID_C))[l];
    float* dst = acc + (size_t)c * HID_C + l * 4;
    atomicAdd(dst + 0, wt * v.x);
    atomicAdd(dst + 1, wt * v.y);
    atomicAdd(dst + 2, wt * v.z);
    atomicAdd(dst + 3, wt * v.w);
}

// out[n][c] = relu( dis[n] * (hs[n][c] + acc[n][c]) + bias[c] )   (hs lives in d_out)
__global__ __launch_bounds__(256) void k_final(const float* __restrict__ acc,
                                               const float* __restrict__ deg,
                                               const float* __restrict__ bias,
                                               float* __restrict__ out, int N) {
    int gid = blockIdx.x * 256 + threadIdx.x;   // one float4 per thread
    int n = gid >> 5;
    int l = gid & 31;
    if (n >= N) return;
    float dis = rsqrtf(deg[n]);
    float4 h = ((const float4*)(out + (size_t)n * HID_C))[l];
    float4 a = ((const float4*)(acc + (size_t)n * HID_C))[l];
    float4 b = ((const float4*)bias)[l];
    float4 o;
    o.x = fmaxf(dis * (h.x + a.x) + b.x, 0.f);
    o.y = fmaxf(dis * (h.y + a.y) + b.y, 0.f);
    o.z = fmaxf(dis * (h.z + a.z) + b.z, 0.f);
    o.w = fmaxf(dis * (h.w + a.w) + b.w, 0.f);
    ((float4*)(out + (size_t)n * HID_C))[l] = o;
}

extern "C" void kernel_launch(void* const* d_in, const int* in_sizes, int n_in,
                              void* d_out, int out_size, void* d_ws, size_t ws_size,
                              hipStream_t stream) {
    const float* x    = (const float*)d_in[0];
    const int*   ei   = (const int*)d_in[1];
    const float* w    = (const float*)d_in[2];
    const float* W    = (const float*)d_in[3];
    const float* bias = (const float*)d_in[4];
    float* out = (float*)d_out;

    const int N = in_sizes[0] / IN_C;
    const int E = in_sizes[2];
    const int* row = ei;        // edge_index[0]
    const int* col = ei + E;    // edge_index[1]

    // workspace layout: deg [N floats] | acc [N*128 floats]
    float* deg = (float*)d_ws;
    size_t deg_bytes_aligned = (((size_t)N * 4 + 255) / 256) * 256;
    float* acc = (float*)((char*)d_ws + deg_bytes_aligned);

    k_init_deg<<<(N + 255) / 256, 256, 0, stream>>>(deg, N);
    k_edge_deg<<<(E + 255) / 256, 256, 0, stream>>>(col, w, deg, E);
    hipMemsetAsync(acc, 0, (size_t)N * HID_C * sizeof(float), stream);

    // hs staged in d_out
    k_gemm_hs<<<512, 256, 0, stream>>>(x, W, deg, out, N);

    long long sth = (long long)E * 32;
    k_scatter<<<(int)((sth + 255) / 256), 256, 0, stream>>>(row, col, w, out, acc, E);

    long long fth = (long long)N * 32;
    k_final<<<(int)((fth + 255) / 256), 256, 0, stream>>>(acc, deg, bias, out, N);
}

// Round 2
// 338.475 us; speedup vs baseline: 4.5186x; 4.5186x over previous
//
#include <hip/hip_runtime.h>
#include <hip/hip_bf16.h>

// GCN layer, algebraically refactored:
//   hs[n]  = (x[n] @ W) * dis[n],   dis[n] = rsqrt(deg[n]),  deg[n] = 1 + sum_{e: col=n} w[e]
//   out[n] = relu( dis[n] * ( hs[n] + sum_{e: col=n} w[e] * hs[row[e]] ) + bias )
// Identical to PyG GCNConv (self-loops, symmetric norm) + ReLU.
//
// Aggregation is PULL-based over an on-device-built CSR (by destination):
// no per-channel atomics (previous version: 102M HBM-side atomic RMWs = 1.6GB writes).

#define IN_C 128
#define HID_C 128
#define GEMM_ROWS 8

// ---------- degree + in-degree histogram ----------
__global__ __launch_bounds__(256) void k_init(float* deg, int* cnt, int N) {
    int i = blockIdx.x * 256 + threadIdx.x;
    if (i < N) { deg[i] = 1.0f; cnt[i] = 0; }   // self-loop weight 1
}

__global__ __launch_bounds__(256) void k_hist(const int* __restrict__ col,
                                              const float* __restrict__ w,
                                              float* deg, int* cnt, int E) {
    int e = blockIdx.x * 256 + threadIdx.x;
    if (e < E) {
        int c = col[e];
        atomicAdd(&deg[c], w[e]);
        atomicAdd(&cnt[c], 1);
    }
}

// ---------- 3-kernel exclusive scan of cnt -> ptr ----------
__global__ __launch_bounds__(256) void k_scan1(const int* __restrict__ cnt,
                                               int* __restrict__ ptr,
                                               int* __restrict__ bsum, int N) {
    __shared__ int sm[256];
    int t = threadIdx.x;
    int i = blockIdx.x * 256 + t;
    int v = (i < N) ? cnt[i] : 0;
    int s = v;
    sm[t] = s;
    __syncthreads();
    for (int off = 1; off < 256; off <<= 1) {
        int add = (t >= off) ? sm[t - off] : 0;
        __syncthreads();
        s += add;
        sm[t] = s;
        __syncthreads();
    }
    if (i < N) ptr[i] = s - v;                 // exclusive within block
    if (t == 255) bsum[blockIdx.x] = s;        // block total
}

__global__ __launch_bounds__(256) void k_scan2(int* __restrict__ bsum, int nb) {
    __shared__ int sm[256];
    int t = threadIdx.x;
    int v = (t < nb) ? bsum[t] : 0;
    int s = v;
    sm[t] = s;
    __syncthreads();
    for (int off = 1; off < 256; off <<= 1) {
        int add = (t >= off) ? sm[t - off] : 0;
        __syncthreads();
        s += add;
        sm[t] = s;
        __syncthreads();
    }
    if (t < nb) bsum[t] = s - v;               // exclusive block offsets
}

__global__ __launch_bounds__(256) void k_scan3(int* __restrict__ ptr,
                                               int* __restrict__ cursor,
                                               const int* __restrict__ bsum, int N) {
    int i = blockIdx.x * 256 + threadIdx.x;
    if (i < N) {
        int p = ptr[i] + bsum[blockIdx.x];
        ptr[i] = p;
        cursor[i] = p;
    }
}

// ---------- counting-sort edges by destination: sedge[pos] = (row, w) ----------
__global__ __launch_bounds__(256) void k_sort(const int* __restrict__ row,
                                              const int* __restrict__ col,
                                              const float* __restrict__ w,
                                              int* __restrict__ cursor,
                                              int2* __restrict__ sedge, int E) {
    int e = blockIdx.x * 256 + threadIdx.x;
    if (e < E) {
        int c = col[e];
        int pos = atomicAdd(&cursor[c], 1);
        int2 rec;
        rec.x = row[e];
        rec.y = __float_as_int(w[e]);
        sedge[pos] = rec;
    }
}

// ---------- hs = (x @ W) * rsqrt(deg), W staged in LDS ----------
__global__ __launch_bounds__(256) void k_gemm_hs(const float* __restrict__ x,
                                                 const float* __restrict__ W,
                                                 const float* __restrict__ deg,
                                                 float* __restrict__ hs, int N) {
    __shared__ float Ws[IN_C * HID_C];        // 64 KB
    __shared__ float xs[GEMM_ROWS][IN_C];     // 4 KB

    const int t = threadIdx.x;
    for (int i = t; i < IN_C * HID_C / 4; i += 256)
        ((float4*)Ws)[i] = ((const float4*)W)[i];
    __syncthreads();

    const int r  = t >> 5;          // 0..7
    const int c0 = (t & 31) * 4;    // 0..124

    for (int base = blockIdx.x * GEMM_ROWS; base < N; base += gridDim.x * GEMM_ROWS) {
        int nrows = min(GEMM_ROWS, N - base);
        for (int i = t; i < nrows * (IN_C / 4); i += 256)
            ((float4*)xs)[i] = ((const float4*)(x + (size_t)base * IN_C))[i];
        __syncthreads();

        if (r < nrows) {
            float a0 = 0.f, a1 = 0.f, a2 = 0.f, a3 = 0.f;
            #pragma unroll 8
            for (int k = 0; k < IN_C; ++k) {
                float a = xs[r][k];
                float4 wv = *(const float4*)&Ws[k * HID_C + c0];
                a0 = fmaf(a, wv.x, a0);
                a1 = fmaf(a, wv.y, a1);
                a2 = fmaf(a, wv.z, a2);
                a3 = fmaf(a, wv.w, a3);
            }
            float dis = rsqrtf(deg[base + r]);
            float4 o = {a0 * dis, a1 * dis, a2 * dis, a3 * dis};
            *(float4*)&hs[(size_t)(base + r) * HID_C + c0] = o;
        }
        __syncthreads();
    }
}

// ---------- pull aggregation: one wave (64 lanes, float2/lane) per node ----------
__global__ __launch_bounds__(256) void k_aggregate(const float* __restrict__ hs,
                                                   const int2* __restrict__ sedge,
                                                   const int* __restrict__ ptr,
                                                   const int* __restrict__ pend,
                                                   const float* __restrict__ deg,
                                                   const float* __restrict__ bias,
                                                   float* __restrict__ out, int N) {
    int t = threadIdx.x;
    int n = blockIdx.x * 4 + (t >> 6);   // 4 waves -> 4 nodes per block
    if (n >= N) return;
    int lane = t & 63;                   // float2 per lane covers 128 channels

    int start = ptr[n];
    int end   = pend[n];                 // cursor after sort == ptr + cnt

    float2 acc = ((const float2*)(hs + (size_t)n * HID_C))[lane];  // self term
    for (int p = start; p < end; ++p) {
        int2 e = sedge[p];               // wave-uniform broadcast load
        float wt = __int_as_float(e.y);
        float2 v = ((const float2*)(hs + (size_t)e.x * HID_C))[lane];
        acc.x = fmaf(wt, v.x, acc.x);
        acc.y = fmaf(wt, v.y, acc.y);
    }
    float dis = rsqrtf(deg[n]);
    float2 b = ((const float2*)bias)[lane];
    float2 o;
    o.x = fmaxf(fmaf(dis, acc.x, b.x), 0.f);
    o.y = fmaxf(fmaf(dis, acc.y, b.y), 0.f);
    ((float2*)(out + (size_t)n * HID_C))[lane] = o;
}

extern "C" void kernel_launch(void* const* d_in, const int* in_sizes, int n_in,
                              void* d_out, int out_size, void* d_ws, size_t ws_size,
                              hipStream_t stream) {
    const float* x    = (const float*)d_in[0];
    const int*   ei   = (const int*)d_in[1];
    const float* w    = (const float*)d_in[2];
    const float* W    = (const float*)d_in[3];
    const float* bias = (const float*)d_in[4];
    float* out = (float*)d_out;

    const int N = in_sizes[0] / IN_C;
    const int E = in_sizes[2];
    const int* row = ei;        // edge_index[0] (source)
    const int* col = ei + E;    // edge_index[1] (destination)

    // workspace layout (256B-aligned):
    // deg[N] f32 | cnt[N] i32 | ptr[N] i32 | cursor[N] i32 | bsum[256] i32
    // | sedge[E] int2 | hs[N*128] f32
    auto alup = [](size_t v) { return (v + 255) & ~(size_t)255; };
    char* p = (char*)d_ws;
    float* deg    = (float*)p;  p += alup((size_t)N * 4);
    int*   cnt    = (int*)p;    p += alup((size_t)N * 4);
    int*   ptr    = (int*)p;    p += alup((size_t)N * 4);
    int*   cursor = (int*)p;    p += alup((size_t)N * 4);
    int*   bsum   = (int*)p;    p += alup(256 * 4);
    int2*  sedge  = (int2*)p;   p += alup((size_t)E * 8);
    float* hs     = (float*)p;  p += alup((size_t)N * HID_C * 4);

    const int NB = (N + 255) / 256;   // scan blocks (196 <= 256)

    k_init<<<NB, 256, 0, stream>>>(deg, cnt, N);
    k_hist<<<(E + 255) / 256, 256, 0, stream>>>(col, w, deg, cnt, E);

    k_scan1<<<NB, 256, 0, stream>>>(cnt, ptr, bsum, N);
    k_scan2<<<1, 256, 0, stream>>>(bsum, NB);
    k_scan3<<<NB, 256, 0, stream>>>(ptr, cursor, bsum, N);

    k_sort<<<(E + 255) / 256, 256, 0, stream>>>(row, col, w, cursor, sedge, E);

    k_gemm_hs<<<512, 256, 0, stream>>>(x, W, deg, hs, N);

    k_aggregate<<<(N + 3) / 4, 256, 0, stream>>>(hs, sedge, ptr, cursor, deg, bias, out, N);
}

// Round 3
// 245.494 us; speedup vs baseline: 6.2300x; 1.3787x over previous
//
#include <hip/hip_runtime.h>
#include <hip/hip_bf16.h>

// GCN layer, algebraically refactored:
//   hs[n]  = (x[n] @ W) * dis[n],   dis[n] = rsqrt(1 + sum_{e: col=n} w[e])
//   out[n] = relu( dis[n] * ( hs[n] + sum_{e: col=n} w[e] * hs[row[e]] ) + bias )
// Identical to PyG GCNConv (self-loops, symmetric norm) + ReLU.
// hs stored bf16 (fp32 accumulate everywhere); pull-based CSR aggregation.

#define IN_C 128
#define HID_C 128
#define DEG_SCALE 16777216.0f   // 2^24 fixed-point for weighted degree

// ---------- bf16 helpers (manual RNE) ----------
__device__ inline unsigned f2bf(float f) {
    unsigned u = __float_as_uint(f);
    return (u + 0x7FFFu + ((u >> 16) & 1u)) >> 16;
}
__device__ inline float bf_lo(unsigned v) { return __uint_as_float(v << 16); }
__device__ inline float bf_hi(unsigned v) { return __uint_as_float(v & 0xFFFF0000u); }

__device__ inline float dis_of(unsigned long long packed) {
    float deg = (float)(unsigned)(packed & 0xFFFFFFFFULL) * (1.0f / DEG_SCALE);
    return rsqrtf(1.0f + deg);
}

// ---------- histogram: one u64 atomic per edge (cnt hi32 | fixedpoint-deg lo32) ----------
__global__ __launch_bounds__(256) void k_hist(const int* __restrict__ col,
                                              const float* __restrict__ w,
                                              unsigned long long* __restrict__ packed, int E) {
    int e = blockIdx.x * 256 + threadIdx.x;
    if (e < E) {
        unsigned long long rec =
            (1ULL << 32) | (unsigned long long)(unsigned)(w[e] * DEG_SCALE + 0.5f);
        atomicAdd(&packed[col[e]], rec);
    }
}

// ---------- 3-kernel exclusive scan of cnt -> ptr ----------
__global__ __launch_bounds__(256) void k_scan1(const unsigned long long* __restrict__ packed,
                                               int* __restrict__ ptr,
                                               int* __restrict__ bsum, int N) {
    __shared__ int sm[256];
    int t = threadIdx.x;
    int i = blockIdx.x * 256 + t;
    int v = (i < N) ? (int)(packed[i] >> 32) : 0;
    int s = v;
    sm[t] = s;
    __syncthreads();
    for (int off = 1; off < 256; off <<= 1) {
        int add = (t >= off) ? sm[t - off] : 0;
        __syncthreads();
        s += add;
        sm[t] = s;
        __syncthreads();
    }
    if (i < N) ptr[i] = s - v;
    if (t == 255) bsum[blockIdx.x] = s;
}

__global__ __launch_bounds__(256) void k_scan2(int* __restrict__ bsum, int nb) {
    __shared__ int sm[256];
    int t = threadIdx.x;
    int v = (t < nb) ? bsum[t] : 0;
    int s = v;
    sm[t] = s;
    __syncthreads();
    for (int off = 1; off < 256; off <<= 1) {
        int add = (t >= off) ? sm[t - off] : 0;
        __syncthreads();
        s += add;
        sm[t] = s;
        __syncthreads();
    }
    if (t < nb) bsum[t] = s - v;
}

__global__ __launch_bounds__(256) void k_scan3(int* __restrict__ ptr,
                                               int* __restrict__ cursor,
                                               const int* __restrict__ bsum, int N) {
    int i = blockIdx.x * 256 + threadIdx.x;
    if (i < N) {
        int p = ptr[i] + bsum[blockIdx.x];
        ptr[i] = p;
        cursor[i] = p;
    }
}

// ---------- counting-sort edges by destination: sedge[pos] = (row, w) ----------
__global__ __launch_bounds__(256) void k_sort(const int* __restrict__ row,
                                              const int* __restrict__ col,
                                              const float* __restrict__ w,
                                              int* __restrict__ cursor,
                                              int2* __restrict__ sedge, int E) {
    int e = blockIdx.x * 256 + threadIdx.x;
    if (e < E) {
        int c = col[e];
        int pos = atomicAdd(&cursor[c], 1);
        int2 rec;
        rec.x = row[e];
        rec.y = __float_as_int(w[e]);
        sedge[pos] = rec;
    }
}

// ---------- register-tiled GEMM: hs(bf16) = (x @ W) * dis ----------
// 64 rows x 128 cols per block, 256 threads: 8 rows x 4 cols per thread, KT=64.
#define BM 64
#define KT 64
__global__ __launch_bounds__(256) void k_gemm_hs(const float* __restrict__ x,
                                                 const float* __restrict__ W,
                                                 const unsigned long long* __restrict__ packed,
                                                 unsigned int* __restrict__ hsb, int N) {
    __shared__ float xs[BM][KT];      // 16 KB
    __shared__ float ws[KT][HID_C];   // 32 KB

    const int t  = threadIdx.x;
    const int rt = t >> 5;            // 0..7 (row group of 8)
    const int c0 = (t & 31) * 4;      // output cols c0..c0+3

    for (int base = blockIdx.x * BM; base < N; base += gridDim.x * BM) {
        float acc[8][4];
        #pragma unroll
        for (int r = 0; r < 8; ++r)
            #pragma unroll
            for (int c = 0; c < 4; ++c) acc[r][c] = 0.f;

        for (int ks = 0; ks < IN_C; ks += KT) {
            // stage x tile: 64 rows x 16 float4
            for (int i = t; i < BM * (KT / 4); i += 256) {
                int r = i >> 4, c4 = i & 15;
                int gr = base + r; if (gr >= N) gr = N - 1;
                ((float4*)&xs[r][0])[c4] =
                    *(const float4*)&x[(size_t)gr * IN_C + ks + c4 * 4];
            }
            // stage W tile: 64 rows x 32 float4
            for (int i = t; i < KT * (HID_C / 4); i += 256) {
                int r = i >> 5, c4 = i & 31;
                ((float4*)&ws[r][0])[c4] =
                    *(const float4*)&W[(size_t)(ks + r) * HID_C + c4 * 4];
            }
            __syncthreads();

            for (int k = 0; k < KT; k += 4) {
                float4 xv[8];
                #pragma unroll
                for (int r = 0; r < 8; ++r) xv[r] = *(float4*)&xs[rt * 8 + r][k];
                #pragma unroll
                for (int kk = 0; kk < 4; ++kk) {
                    float4 wv = *(float4*)&ws[k + kk][c0];
                    #pragma unroll
                    for (int r = 0; r < 8; ++r) {
                        float a = (kk == 0) ? xv[r].x : (kk == 1) ? xv[r].y
                                : (kk == 2) ? xv[r].z : xv[r].w;
                        acc[r][0] = fmaf(a, wv.x, acc[r][0]);
                        acc[r][1] = fmaf(a, wv.y, acc[r][1]);
                        acc[r][2] = fmaf(a, wv.z, acc[r][2]);
                        acc[r][3] = fmaf(a, wv.w, acc[r][3]);
                    }
                }
            }
            __syncthreads();
        }

        #pragma unroll
        for (int r = 0; r < 8; ++r) {
            int n = base + rt * 8 + r;
            if (n < N) {
                float dis = dis_of(packed[n]);
                uint2 o;
                o.x = (f2bf(acc[r][1] * dis) << 16) | f2bf(acc[r][0] * dis);
                o.y = (f2bf(acc[r][3] * dis) << 16) | f2bf(acc[r][2] * dis);
                *(uint2*)&hsb[(size_t)n * (HID_C / 2) + (c0 >> 1)] = o;
            }
        }
    }
}

// ---------- pull aggregation: one wave per node, bf16 gather, fp32 accumulate ----------
__global__ __launch_bounds__(256) void k_aggregate(const unsigned int* __restrict__ hsb,
                                                   const int2* __restrict__ sedge,
                                                   const int* __restrict__ ptr,
                                                   const int* __restrict__ pend,
                                                   const unsigned long long* __restrict__ packed,
                                                   const float* __restrict__ bias,
                                                   float* __restrict__ out, int N) {
    int t = threadIdx.x;
    int n = blockIdx.x * 4 + (t >> 6);
    if (n >= N) return;
    int lane = t & 63;                 // covers channels 2*lane, 2*lane+1

    int p   = ptr[n];
    int end = pend[n];

    unsigned sv = hsb[(size_t)n * (HID_C / 2) + lane];   // self term
    float2 acc = { bf_lo(sv), bf_hi(sv) };

    #pragma unroll 4
    for (; p < end; ++p) {
        int2 e = sedge[p];             // wave-uniform
        float wt = __int_as_float(e.y);
        unsigned v = hsb[(size_t)e.x * (HID_C / 2) + lane];
        acc.x = fmaf(wt, bf_lo(v), acc.x);
        acc.y = fmaf(wt, bf_hi(v), acc.y);
    }

    float dis = dis_of(packed[n]);
    float2 b = ((const float2*)bias)[lane];
    float2 o;
    o.x = fmaxf(fmaf(dis, acc.x, b.x), 0.f);
    o.y = fmaxf(fmaf(dis, acc.y, b.y), 0.f);
    ((float2*)(out + (size_t)n * HID_C))[lane] = o;
}

extern "C" void kernel_launch(void* const* d_in, const int* in_sizes, int n_in,
                              void* d_out, int out_size, void* d_ws, size_t ws_size,
                              hipStream_t stream) {
    const float* x    = (const float*)d_in[0];
    const int*   ei   = (const int*)d_in[1];
    const float* w    = (const float*)d_in[2];
    const float* W    = (const float*)d_in[3];
    const float* bias = (const float*)d_in[4];
    float* out = (float*)d_out;

    const int N = in_sizes[0] / IN_C;
    const int E = in_sizes[2];
    const int* row = ei;        // edge_index[0] (source)
    const int* col = ei + E;    // edge_index[1] (destination)

    // workspace: packed[N] u64 | ptr[N] i32 | cursor[N] i32 | bsum[256] i32
    //            | sedge[E] int2 | hsb[N*64] u32
    auto alup = [](size_t v) { return (v + 255) & ~(size_t)255; };
    char* p = (char*)d_ws;
    unsigned long long* packed = (unsigned long long*)p; p += alup((size_t)N * 8);
    int*   ptr    = (int*)p;    p += alup((size_t)N * 4);
    int*   cursor = (int*)p;    p += alup((size_t)N * 4);
    int*   bsum   = (int*)p;    p += alup(256 * 4);
    int2*  sedge  = (int2*)p;   p += alup((size_t)E * 8);
    unsigned int* hsb = (unsigned int*)p; p += alup((size_t)N * (HID_C / 2) * 4);

    const int NB = (N + 255) / 256;   // 196 <= 256

    hipMemsetAsync(packed, 0, (size_t)N * 8, stream);
    k_hist<<<(E + 255) / 256, 256, 0, stream>>>(col, w, packed, E);

    k_scan1<<<NB, 256, 0, stream>>>(packed, ptr, bsum, N);
    k_scan2<<<1, 256, 0, stream>>>(bsum, NB);
    k_scan3<<<NB, 256, 0, stream>>>(ptr, cursor, bsum, N);

    k_sort<<<(E + 255) / 256, 256, 0, stream>>>(row, col, w, cursor, sedge, E);

    k_gemm_hs<<<768, 256, 0, stream>>>(x, W, packed, hsb, N);

    k_aggregate<<<(N + 3) / 4, 256, 0, stream>>>(hsb, sedge, ptr, cursor, packed, bias, out, N);
}

// Round 4
// 196.667 us; speedup vs baseline: 7.7768x; 1.2483x over previous
//
#include <hip/hip_runtime.h>
#include <hip/hip_bf16.h>

// GCN layer, algebraically refactored:
//   hs[n]  = (x[n] @ W) * dis[n],   dis[n] = rsqrt(1 + sum_{e: col=n} w[e])
//   out[n] = relu( dis[n] * ( hs[n] + sum_{e: col=n} w[e] * hs[row[e]] ) + bias )
// Identical to PyG GCNConv (self-loops, symmetric norm) + ReLU.
// hs stored bf16 (fp32 accumulate); pull-based CSR aggregation.
// CSR built via 2-pass radix partition (256-node buckets) with LDS staging:
// no scattered 8B writes (prev k_sort: 52MB line-RMW traffic), histogram and
// scan folded into the bucket passes as LDS atomics/scans.

#define IN_C 128
#define HID_C 128
#define CAP 6144          // per-bucket edge capacity (mean 4082, +32 sigma)
#define EPB 8192          // edges per pass-A block (32 per thread)

// ---------- bf16 helpers (manual RNE) ----------
__device__ inline unsigned f2bf(float f) {
    unsigned u = __float_as_uint(f);
    return (u + 0x7FFFu + ((u >> 16) & 1u)) >> 16;
}
__device__ inline float bf_lo(unsigned v) { return __uint_as_float(v << 16); }
__device__ inline float bf_hi(unsigned v) { return __uint_as_float(v & 0xFFFF0000u); }

// ---------- pass A: radix partition edges into 256-node buckets ----------
__global__ __launch_bounds__(256) void k_passA(const int* __restrict__ row,
                                               const int* __restrict__ col,
                                               const float* __restrict__ w,
                                               int* __restrict__ gcur,
                                               int2* __restrict__ bedge,
                                               int E, int NBK) {
    __shared__ int hist[256], base_s[256], cur[256];
    const int t = threadIdx.x;
    const int e0 = blockIdx.x * EPB;
    const int e1 = min(E, e0 + EPB);

    hist[t] = 0;
    __syncthreads();

    int cbuf[32];
    #pragma unroll
    for (int i = 0; i < 32; ++i) {
        int e = e0 + t + i * 256;
        int c = (e < e1) ? col[e] : -1;
        cbuf[i] = c;
        if (c >= 0) atomicAdd(&hist[c >> 8], 1);
    }
    __syncthreads();

    if (t < NBK && hist[t] > 0) base_s[t] = atomicAdd(&gcur[t], hist[t]);
    cur[t] = 0;
    __syncthreads();

    #pragma unroll
    for (int i = 0; i < 32; ++i) {
        int c = cbuf[i];
        if (c >= 0) {
            int e = e0 + t + i * 256;
            int b = c >> 8;
            int lpos = atomicAdd(&cur[b], 1);
            int2 rec;
            rec.x = ((c & 255) << 24) | row[e];   // col_local | row (row < 2^24)
            rec.y = __float_as_int(w[e]);
            bedge[(size_t)b * CAP + base_s[b] + lpos] = rec;
        }
    }
}

// ---------- tiny scan: bucket counts -> bucket edge bases; ptr[N]=E sentinel ----------
__global__ __launch_bounds__(256) void k_scanS(const int* __restrict__ gcur,
                                               int* __restrict__ ebase,
                                               int* __restrict__ ptr,
                                               int E, int N, int NBK) {
    __shared__ int sm[256];
    int t = threadIdx.x;
    int v = (t < NBK) ? gcur[t] : 0;
    int s = v;
    sm[t] = s;
    __syncthreads();
    for (int off = 1; off < 256; off <<= 1) {
        int add = (t >= off) ? sm[t - off] : 0;
        __syncthreads();
        s += add;
        sm[t] = s;
        __syncthreads();
    }
    if (t < NBK) ebase[t] = s - v;
    if (t == 0) ptr[N] = E;
}

// ---------- pass B: per-bucket — degree, dis, CSR ptr, final edge placement ----------
__global__ __launch_bounds__(256) void k_passB(const int2* __restrict__ bedge,
                                               const int* __restrict__ gcnt,
                                               const int* __restrict__ ebase,
                                               int2* __restrict__ sedge,
                                               int* __restrict__ ptr,
                                               float* __restrict__ dis,
                                               int N) {
    __shared__ float wdeg[256];
    __shared__ int cnt[256], cur[256], sm[256];
    const int b = blockIdx.x;
    const int t = threadIdx.x;
    const int nb0 = b << 8;
    const int ecnt = gcnt[b];
    const int eb = ebase[b];
    const int2* be = bedge + (size_t)b * CAP;

    wdeg[t] = 0.f;
    cnt[t] = 0;
    __syncthreads();

    for (int p = t; p < ecnt; p += 256) {
        int2 rec = be[p];
        int cl = (rec.x >> 24) & 255;
        atomicAdd(&cnt[cl], 1);
        atomicAdd(&wdeg[cl], __int_as_float(rec.y));   // LDS f32 atomic
    }
    __syncthreads();

    // exclusive scan of per-node counts
    int v = cnt[t];
    int s = v;
    sm[t] = s;
    __syncthreads();
    for (int off = 1; off < 256; off <<= 1) {
        int add = (t >= off) ? sm[t - off] : 0;
        __syncthreads();
        s += add;
        sm[t] = s;
        __syncthreads();
    }
    int excl = s - v;
    cur[t] = excl;
    int n = nb0 + t;
    if (n < N) {
        dis[n] = rsqrtf(1.0f + wdeg[t]);
        ptr[n] = eb + excl;
    }
    __syncthreads();

    for (int p = t; p < ecnt; p += 256) {
        int2 rec = be[p];
        int cl = (rec.x >> 24) & 255;
        int lpos = atomicAdd(&cur[cl], 1);
        int2 o;
        o.x = rec.x & 0xFFFFFF;
        o.y = rec.y;
        sedge[eb + lpos] = o;
    }
}

// ---------- register-tiled GEMM: hs(bf16) = (x @ W) * dis ----------
#define BM 64
#define KT 64
__global__ __launch_bounds__(256) void k_gemm_hs(const float* __restrict__ x,
                                                 const float* __restrict__ W,
                                                 const float* __restrict__ dis,
                                                 unsigned int* __restrict__ hsb, int N) {
    __shared__ float xs[BM][KT];      // 16 KB
    __shared__ float ws[KT][HID_C];   // 32 KB

    const int t  = threadIdx.x;
    const int rt = t >> 5;            // 0..7
    const int c0 = (t & 31) * 4;      // output cols c0..c0+3

    for (int base = blockIdx.x * BM; base < N; base += gridDim.x * BM) {
        float acc[8][4];
        #pragma unroll
        for (int r = 0; r < 8; ++r)
            #pragma unroll
            for (int c = 0; c < 4; ++c) acc[r][c] = 0.f;

        for (int ks = 0; ks < IN_C; ks += KT) {
            for (int i = t; i < BM * (KT / 4); i += 256) {
                int r = i >> 4, c4 = i & 15;
                int gr = base + r; if (gr >= N) gr = N - 1;
                ((float4*)&xs[r][0])[c4] =
                    *(const float4*)&x[(size_t)gr * IN_C + ks + c4 * 4];
            }
            for (int i = t; i < KT * (HID_C / 4); i += 256) {
                int r = i >> 5, c4 = i & 31;
                ((float4*)&ws[r][0])[c4] =
                    *(const float4*)&W[(size_t)(ks + r) * HID_C + c4 * 4];
            }
            __syncthreads();

            for (int k = 0; k < KT; k += 4) {
                float4 xv[8];
                #pragma unroll
                for (int r = 0; r < 8; ++r) xv[r] = *(float4*)&xs[rt * 8 + r][k];
                #pragma unroll
                for (int kk = 0; kk < 4; ++kk) {
                    float4 wv = *(float4*)&ws[k + kk][c0];
                    #pragma unroll
                    for (int r = 0; r < 8; ++r) {
                        float a = (kk == 0) ? xv[r].x : (kk == 1) ? xv[r].y
                                : (kk == 2) ? xv[r].z : xv[r].w;
                        acc[r][0] = fmaf(a, wv.x, acc[r][0]);
                        acc[r][1] = fmaf(a, wv.y, acc[r][1]);
                        acc[r][2] = fmaf(a, wv.z, acc[r][2]);
                        acc[r][3] = fmaf(a, wv.w, acc[r][3]);
                    }
                }
            }
            __syncthreads();
        }

        #pragma unroll
        for (int r = 0; r < 8; ++r) {
            int n = base + rt * 8 + r;
            if (n < N) {
                float d = dis[n];
                uint2 o;
                o.x = (f2bf(acc[r][1] * d) << 16) | f2bf(acc[r][0] * d);
                o.y = (f2bf(acc[r][3] * d) << 16) | f2bf(acc[r][2] * d);
                *(uint2*)&hsb[(size_t)n * (HID_C / 2) + (c0 >> 1)] = o;
            }
        }
    }
}

// ---------- pull aggregation: one wave per node, bf16 gather, fp32 accumulate ----------
__global__ __launch_bounds__(256) void k_aggregate(const unsigned int* __restrict__ hsb,
                                                   const int2* __restrict__ sedge,
                                                   const int* __restrict__ ptr,
                                                   const float* __restrict__ dis,
                                                   const float* __restrict__ bias,
                                                   float* __restrict__ out, int N) {
    int t = threadIdx.x;
    int n = blockIdx.x * 4 + (t >> 6);
    if (n >= N) return;
    int lane = t & 63;                 // channels 2*lane, 2*lane+1

    int p   = ptr[n];
    int end = ptr[n + 1];

    unsigned sv = hsb[(size_t)n * (HID_C / 2) + lane];   // self term
    float2 acc = { bf_lo(sv), bf_hi(sv) };

    #pragma unroll 8
    for (; p < end; ++p) {
        int2 e = sedge[p];             // wave-uniform
        float wt = __int_as_float(e.y);
        unsigned v = hsb[(size_t)e.x * (HID_C / 2) + lane];
        acc.x = fmaf(wt, bf_lo(v), acc.x);
        acc.y = fmaf(wt, bf_hi(v), acc.y);
    }

    float d = dis[n];
    float2 bv = ((const float2*)bias)[lane];
    float2 o;
    o.x = fmaxf(fmaf(d, acc.x, bv.x), 0.f);
    o.y = fmaxf(fmaf(d, acc.y, bv.y), 0.f);
    ((float2*)(out + (size_t)n * HID_C))[lane] = o;
}

extern "C" void kernel_launch(void* const* d_in, const int* in_sizes, int n_in,
                              void* d_out, int out_size, void* d_ws, size_t ws_size,
                              hipStream_t stream) {
    const float* x    = (const float*)d_in[0];
    const int*   ei   = (const int*)d_in[1];
    const float* w    = (const float*)d_in[2];
    const float* W    = (const float*)d_in[3];
    const float* bias = (const float*)d_in[4];
    float* out = (float*)d_out;

    const int N = in_sizes[0] / IN_C;
    const int E = in_sizes[2];
    const int* row = ei;        // edge_index[0] (source)
    const int* col = ei + E;    // edge_index[1] (destination)
    const int NBK = (N + 255) >> 8;   // 196 buckets of 256 nodes

    // workspace: gcur[256] | ebase[256] | ptr[N+1] | dis[N]
    //            | bedge[NBK*CAP] int2 | sedge[E] int2 | hsb[N*64] u32
    auto alup = [](size_t v) { return (v + 255) & ~(size_t)255; };
    char* p = (char*)d_ws;
    int*   gcur  = (int*)p;   p += alup(256 * 4);
    int*   ebase = (int*)p;   p += alup(256 * 4);
    int*   ptr   = (int*)p;   p += alup(((size_t)N + 1) * 4);
    float* dis   = (float*)p; p += alup((size_t)N * 4);
    int2*  bedge = (int2*)p;  p += alup((size_t)NBK * CAP * 8);
    int2*  sedge = (int2*)p;  p += alup((size_t)E * 8);
    unsigned int* hsb = (unsigned int*)p; p += alup((size_t)N * (HID_C / 2) * 4);

    hipMemsetAsync(gcur, 0, 256 * 4, stream);

    k_passA<<<(E + EPB - 1) / EPB, 256, 0, stream>>>(row, col, w, gcur, bedge, E, NBK);
    k_scanS<<<1, 256, 0, stream>>>(gcur, ebase, ptr, E, N, NBK);
    k_passB<<<NBK, 256, 0, stream>>>(bedge, gcur, ebase, sedge, ptr, dis, N);

    k_gemm_hs<<<(N + BM - 1) / BM, 256, 0, stream>>>(x, W, dis, hsb, N);

    k_aggregate<<<(N + 3) / 4, 256, 0, stream>>>(hsb, sedge, ptr, dis, bias, out, N);
}

// Round 7
// 187.866 us; speedup vs baseline: 8.1411x; 1.0468x over previous
//
#include <hip/hip_runtime.h>
#include <hip/hip_bf16.h>

// GCN layer, algebraically refactored:
//   hs[n]  = (x[n] @ W) * dis[n],   dis[n] = rsqrt(1 + sum_{e: col=n} w[e])
//   out[n] = relu( dis[n] * ( hs[n] + sum_{e: col=n} w[e] * hs[row[e]] ) + bias )
// Identical to PyG GCNConv (self-loops, symmetric norm) + ReLU.
// hs stored bf16; GEMM bf16 MFMA (fp32 accumulate); pull-based CSR aggregation.
// CSR built via 2-pass radix partition (256-node buckets); bucket scan folded into passB.

#define IN_C 128
#define HID_C 128
#define CAP 6144          // per-bucket edge capacity (mean 4082, +32 sigma)
#define EPB 8192          // edges per pass-A block (32 per thread)

typedef __attribute__((ext_vector_type(8))) short bf16x8;
typedef __attribute__((ext_vector_type(4))) float f32x4;

// ---------- bf16 helpers (manual RNE) ----------
__device__ inline unsigned f2bf(float f) {
    unsigned u = __float_as_uint(f);
    return (u + 0x7FFFu + ((u >> 16) & 1u)) >> 16;
}
__device__ inline float bf_lo(unsigned v) { return __uint_as_float(v << 16); }
__device__ inline float bf_hi(unsigned v) { return __uint_as_float(v & 0xFFFF0000u); }

// ---------- pass A: radix partition edges into 256-node buckets ----------
__global__ __launch_bounds__(256) void k_passA(const int* __restrict__ row,
                                               const int* __restrict__ col,
                                               const float* __restrict__ w,
                                               int* __restrict__ gcur,
                                               int2* __restrict__ bedge,
                                               int E, int NBK) {
    __shared__ int hist[256], base_s[256], cur[256];
    const int t = threadIdx.x;
    const int e0 = blockIdx.x * EPB;
    const int e1 = min(E, e0 + EPB);

    hist[t] = 0;
    __syncthreads();

    int cbuf[32];
    #pragma unroll
    for (int i = 0; i < 32; ++i) {
        int e = e0 + t + i * 256;
        int c = (e < e1) ? col[e] : -1;
        cbuf[i] = c;
        if (c >= 0) atomicAdd(&hist[c >> 8], 1);
    }
    __syncthreads();

    if (t < NBK && hist[t] > 0) base_s[t] = atomicAdd(&gcur[t], hist[t]);
    cur[t] = 0;
    __syncthreads();

    #pragma unroll
    for (int i = 0; i < 32; ++i) {
        int c = cbuf[i];
        if (c >= 0) {
            int e = e0 + t + i * 256;
            int b = c >> 8;
            int lpos = atomicAdd(&cur[b], 1);
            int2 rec;
            rec.x = ((c & 255) << 24) | row[e];   // col_local | row (row < 2^24)
            rec.y = __float_as_int(w[e]);
            bedge[(size_t)b * CAP + base_s[b] + lpos] = rec;
        }
    }
}

// ---------- pass B: per-bucket — bucket scan, degree, dis, CSR ptr, placement ----------
__global__ __launch_bounds__(256) void k_passB(const int2* __restrict__ bedge,
                                               const int* __restrict__ gcur,
                                               int2* __restrict__ sedge,
                                               int* __restrict__ ptr,
                                               float* __restrict__ dis,
                                               int E, int N, int NBK) {
    __shared__ float wdeg[256];
    __shared__ int cnt[256], cur[256], sm[256], ebs[256], cnts[256];
    const int b = blockIdx.x;
    const int t = threadIdx.x;
    const int nb0 = b << 8;

    // redundant per-block exclusive scan of bucket counts -> edge base
    int gv = (t < NBK) ? gcur[t] : 0;
    int gs = gv;
    sm[t] = gs;
    __syncthreads();
    for (int off = 1; off < 256; off <<= 1) {
        int add = (t >= off) ? sm[t - off] : 0;
        __syncthreads();
        gs += add;
        sm[t] = gs;
        __syncthreads();
    }
    ebs[t] = gs - gv;
    cnts[t] = gv;
    wdeg[t] = 0.f;
    cnt[t] = 0;
    __syncthreads();

    const int ecnt = cnts[b];
    const int eb   = ebs[b];
    const int2* be = bedge + (size_t)b * CAP;
    if (b == 0 && t == 0) ptr[N] = E;

    for (int p = t; p < ecnt; p += 256) {
        int2 rec = be[p];
        int cl = (rec.x >> 24) & 255;
        atomicAdd(&cnt[cl], 1);
        atomicAdd(&wdeg[cl], __int_as_float(rec.y));   // LDS f32 atomic
    }
    __syncthreads();

    // exclusive scan of per-node counts
    int v = cnt[t];
    int s = v;
    sm[t] = s;
    __syncthreads();
    for (int off = 1; off < 256; off <<= 1) {
        int add = (t >= off) ? sm[t - off] : 0;
        __syncthreads();
        s += add;
        sm[t] = s;
        __syncthreads();
    }
    int excl = s - v;
    cur[t] = excl;
    int n = nb0 + t;
    if (n < N) {
        dis[n] = rsqrtf(1.0f + wdeg[t]);
        ptr[n] = eb + excl;
    }
    __syncthreads();

    for (int p = t; p < ecnt; p += 256) {
        int2 rec = be[p];
        int cl = (rec.x >> 24) & 255;
        int lpos = atomicAdd(&cur[cl], 1);
        int2 o;
        o.x = rec.x & 0xFFFFFF;
        o.y = rec.y;
        sedge[eb + lpos] = o;
    }
}

// ---------- MFMA GEMM: hs(bf16) = (x @ W) * dis ----------
// 64 rows/block, full 128 cols. 4 waves; wave w owns rows [w*16, w*16+16).
// LDS: x tile bf16 [64][128], W^T bf16 [128][128], both XOR-swizzled
// (ushort idx ^= (row&7)<<3) so 16-lane same-column reads spread across banks (T2).
__global__ __launch_bounds__(256) void k_gemm_hs(const float* __restrict__ x,
                                                 const float* __restrict__ W,
                                                 const float* __restrict__ dis,
                                                 unsigned short* __restrict__ hsb, int N) {
    __shared__ __align__(16) unsigned short xsb[64 * 128];    // 16 KB
    __shared__ __align__(16) unsigned short wsb[128 * 128];   // 32 KB

    const int t = threadIdx.x;
    const int base = blockIdx.x * 64;

    // stage W^T: wsb[n][k] = bf16(W[k][n]); reads coalesced over n
    for (int i = t; i < 128 * 32; i += 256) {
        int n = i & 127;
        int k0 = (i >> 7) * 4;
        ushort4 bv;
        bv.x = (unsigned short)f2bf(W[(size_t)(k0 + 0) * HID_C + n]);
        bv.y = (unsigned short)f2bf(W[(size_t)(k0 + 1) * HID_C + n]);
        bv.z = (unsigned short)f2bf(W[(size_t)(k0 + 2) * HID_C + n]);
        bv.w = (unsigned short)f2bf(W[(size_t)(k0 + 3) * HID_C + n]);
        int idx = (n * 128 + k0) ^ ((n & 7) << 3);   // ushort-index swizzle
        *(ushort4*)&wsb[idx] = bv;
    }
    // stage x tile: xsb[r][k] = bf16(x[base+r][k]); coalesced float4 reads
    for (int i = t; i < 64 * 32; i += 256) {
        int r = i >> 5;
        int c4 = (i & 31) * 4;
        int gr = base + r;
        if (gr >= N) gr = N - 1;
        float4 v = *(const float4*)&x[(size_t)gr * IN_C + c4];
        ushort4 bv;
        bv.x = (unsigned short)f2bf(v.x);
        bv.y = (unsigned short)f2bf(v.y);
        bv.z = (unsigned short)f2bf(v.z);
        bv.w = (unsigned short)f2bf(v.w);
        int idx = (r * 128 + c4) ^ ((r & 7) << 3);
        *(ushort4*)&xsb[idx] = bv;
    }
    __syncthreads();

    const int w  = t >> 6;
    const int l  = t & 63;
    const int lr = l & 15;            // A row / B col within 16
    const int lk = (l >> 4) * 8;      // k offset within 32

    f32x4 acc[8];
    #pragma unroll
    for (int nt = 0; nt < 8; ++nt) acc[nt] = (f32x4){0.f, 0.f, 0.f, 0.f};

    #pragma unroll
    for (int ks = 0; ks < 4; ++ks) {
        int k0 = ks * 32 + lk;
        int arow = w * 16 + lr;
        bf16x8 a = *(const bf16x8*)&xsb[(arow * 128 + k0) ^ ((arow & 7) << 3)];
        #pragma unroll
        for (int nt = 0; nt < 8; ++nt) {
            int bn = nt * 16 + lr;
            bf16x8 bb = *(const bf16x8*)&wsb[(bn * 128 + k0) ^ ((bn & 7) << 3)];
            acc[nt] = __builtin_amdgcn_mfma_f32_16x16x32_bf16(a, bb, acc[nt], 0, 0, 0);
        }
    }

    // epilogue: D row = (l>>4)*4 + j, col = nt*16 + lr (m89-verified layout)
    const int mbase = base + w * 16 + (l >> 4) * 4;
    float d[4];
    #pragma unroll
    for (int j = 0; j < 4; ++j)
        d[j] = (mbase + j < N) ? dis[mbase + j] : 0.f;
    #pragma unroll
    for (int nt = 0; nt < 8; ++nt) {
        int c = nt * 16 + lr;
        #pragma unroll
        for (int j = 0; j < 4; ++j) {
            int n = mbase + j;
            if (n < N)
                hsb[(size_t)n * HID_C + c] = (unsigned short)f2bf(acc[nt][j] * d[j]);
        }
    }
}

// ---------- pull aggregation: one wave per node, bf16 gather, fp32 accumulate ----------
__global__ __launch_bounds__(256) void k_aggregate(const unsigned int* __restrict__ hsb,
                                                   const int2* __restrict__ sedge,
                                                   const int* __restrict__ ptr,
                                                   const float* __restrict__ dis,
                                                   const float* __restrict__ bias,
                                                   float* __restrict__ out, int N) {
    int t = threadIdx.x;
    int n = blockIdx.x * 4 + (t >> 6);
    if (n >= N) return;
    int lane = t & 63;                 // channels 2*lane, 2*lane+1

    int p   = ptr[n];
    int end = ptr[n + 1];

    unsigned sv = hsb[(size_t)n * (HID_C / 2) + lane];   // self term
    float2 acc = { bf_lo(sv), bf_hi(sv) };

    #pragma unroll 8
    for (; p < end; ++p) {
        int2 e = sedge[p];             // wave-uniform
        float wt = __int_as_float(e.y);
        unsigned v = hsb[(size_t)e.x * (HID_C / 2) + lane];
        acc.x = fmaf(wt, bf_lo(v), acc.x);
        acc.y = fmaf(wt, bf_hi(v), acc.y);
    }

    float d = dis[n];
    float2 bv = ((const float2*)bias)[lane];
    float2 o;
    o.x = fmaxf(fmaf(d, acc.x, bv.x), 0.f);
    o.y = fmaxf(fmaf(d, acc.y, bv.y), 0.f);
    ((float2*)(out + (size_t)n * HID_C))[lane] = o;
}

extern "C" void kernel_launch(void* const* d_in, const int* in_sizes, int n_in,
                              void* d_out, int out_size, void* d_ws, size_t ws_size,
                              hipStream_t stream) {
    const float* x    = (const float*)d_in[0];
    const int*   ei   = (const int*)d_in[1];
    const float* w    = (const float*)d_in[2];
    const float* W    = (const float*)d_in[3];
    const float* bias = (const float*)d_in[4];
    float* out = (float*)d_out;

    const int N = in_sizes[0] / IN_C;
    const int E = in_sizes[2];
    const int* row = ei;        // edge_index[0] (source)
    const int* col = ei + E;    // edge_index[1] (destination)
    const int NBK = (N + 255) >> 8;   // 196 buckets of 256 nodes

    // workspace: gcur[256] | ptr[N+1] | dis[N] | bedge[NBK*CAP] int2
    //            | sedge[E] int2 | hsb[N*128] ushort
    auto alup = [](size_t v) { return (v + 255) & ~(size_t)255; };
    char* p = (char*)d_ws;
    int*   gcur  = (int*)p;   p += alup(256 * 4);
    int*   ptr   = (int*)p;   p += alup(((size_t)N + 1) * 4);
    float* dis   = (float*)p; p += alup((size_t)N * 4);
    int2*  bedge = (int2*)p;  p += alup((size_t)NBK * CAP * 8);
    int2*  sedge = (int2*)p;  p += alup((size_t)E * 8);
    unsigned short* hsb = (unsigned short*)p; p += alup((size_t)N * HID_C * 2);

    hipMemsetAsync(gcur, 0, 256 * 4, stream);

    k_passA<<<(E + EPB - 1) / EPB, 256, 0, stream>>>(row, col, w, gcur, bedge, E, NBK);
    k_passB<<<NBK, 256, 0, stream>>>(bedge, gcur, sedge, ptr, dis, E, N, NBK);

    k_gemm_hs<<<(N + 63) / 64, 256, 0, stream>>>(x, W, dis, hsb, N);

    k_aggregate<<<(N + 3) / 4, 256, 0, stream>>>((const unsigned int*)hsb, sedge, ptr,
                                                 dis, bias, out, N);
}

// Round 8
// 181.758 us; speedup vs baseline: 8.4147x; 1.0336x over previous
//
#include <hip/hip_runtime.h>
#include <hip/hip_bf16.h>

// GCN layer, algebraically refactored:
//   hs[n]  = (x[n] @ W) * dis[n],   dis[n] = rsqrt(1 + sum_{e: col=n} w[e])
//   out[n] = relu( dis[n] * ( hs[n] + sum_{e: col=n} w[e] * hs[row[e]] ) + bias )
// Identical to PyG GCNConv (self-loops, symmetric norm) + ReLU.
// hs stored bf16; GEMM bf16 MFMA (fp32 accumulate); pull-based CSR aggregation.
// CSR built via 2-pass radix partition (256-node buckets); bucket scan folded into passB.
// W pre-converted to bf16 W^T (pre-swizzled) ONCE by k_prepW — the round-7 GEMM
// re-staged+re-converted all of W per block (782x redundant scalar loads + f2bf).

#define IN_C 128
#define HID_C 128
#define CAP 6144          // per-bucket edge capacity (mean 4082, +32 sigma)
#define EPB 8192          // edges per pass-A block (32 per thread)

typedef __attribute__((ext_vector_type(8))) short bf16x8;
typedef __attribute__((ext_vector_type(4))) float f32x4;

// ---------- bf16 helpers (manual RNE) ----------
__device__ inline unsigned f2bf(float f) {
    unsigned u = __float_as_uint(f);
    return (u + 0x7FFFu + ((u >> 16) & 1u)) >> 16;
}
__device__ inline float bf_lo(unsigned v) { return __uint_as_float(v << 16); }
__device__ inline float bf_hi(unsigned v) { return __uint_as_float(v & 0xFFFF0000u); }

// ---------- prep: W -> bf16 W^T, pre-swizzled; block 0 also zeroes gcur ----------
// wt[(n*128+k) ^ ((n&7)<<3)] = bf16(W[k][n]);  16 blocks x 256 threads x 4 k-elems.
__global__ __launch_bounds__(256) void k_prepW(const float* __restrict__ W,
                                               unsigned short* __restrict__ wt,
                                               int* __restrict__ gcur) {
    const int t = threadIdx.x;
    if (blockIdx.x == 0) gcur[t] = 0;
    int i = blockIdx.x * 256 + t;          // 0..4095
    int n = i & 127;
    int k0 = (i >> 7) * 4;
    ushort4 bv;
    bv.x = (unsigned short)f2bf(W[(size_t)(k0 + 0) * HID_C + n]);
    bv.y = (unsigned short)f2bf(W[(size_t)(k0 + 1) * HID_C + n]);
    bv.z = (unsigned short)f2bf(W[(size_t)(k0 + 2) * HID_C + n]);
    bv.w = (unsigned short)f2bf(W[(size_t)(k0 + 3) * HID_C + n]);
    int idx = (n * 128 + k0) ^ ((n & 7) << 3);   // ushort-index swizzle
    *(ushort4*)&wt[idx] = bv;
}

// ---------- pass A: radix partition edges into 256-node buckets ----------
__global__ __launch_bounds__(256) void k_passA(const int* __restrict__ row,
                                               const int* __restrict__ col,
                                               const float* __restrict__ w,
                                               int* __restrict__ gcur,
                                               int2* __restrict__ bedge,
                                               int E, int NBK) {
    __shared__ int hist[256], base_s[256], cur[256];
    const int t = threadIdx.x;
    const int e0 = blockIdx.x * EPB;
    const int e1 = min(E, e0 + EPB);

    hist[t] = 0;
    __syncthreads();

    int cbuf[32];
    #pragma unroll
    for (int i = 0; i < 32; ++i) {
        int e = e0 + t + i * 256;
        int c = (e < e1) ? col[e] : -1;
        cbuf[i] = c;
        if (c >= 0) atomicAdd(&hist[c >> 8], 1);
    }
    __syncthreads();

    if (t < NBK && hist[t] > 0) base_s[t] = atomicAdd(&gcur[t], hist[t]);
    cur[t] = 0;
    __syncthreads();

    #pragma unroll
    for (int i = 0; i < 32; ++i) {
        int c = cbuf[i];
        if (c >= 0) {
            int e = e0 + t + i * 256;
            int b = c >> 8;
            int lpos = atomicAdd(&cur[b], 1);
            int2 rec;
            rec.x = ((c & 255) << 24) | row[e];   // col_local | row (row < 2^24)
            rec.y = __float_as_int(w[e]);
            bedge[(size_t)b * CAP + base_s[b] + lpos] = rec;
        }
    }
}

// ---------- pass B: per-bucket — bucket scan, degree, dis, CSR ptr, placement ----------
__global__ __launch_bounds__(256) void k_passB(const int2* __restrict__ bedge,
                                               const int* __restrict__ gcur,
                                               int2* __restrict__ sedge,
                                               int* __restrict__ ptr,
                                               float* __restrict__ dis,
                                               int E, int N, int NBK) {
    __shared__ float wdeg[256];
    __shared__ int cnt[256], cur[256], sm[256], ebs[256], cnts[256];
    const int b = blockIdx.x;
    const int t = threadIdx.x;
    const int nb0 = b << 8;

    // redundant per-block exclusive scan of bucket counts -> edge base
    int gv = (t < NBK) ? gcur[t] : 0;
    int gs = gv;
    sm[t] = gs;
    __syncthreads();
    for (int off = 1; off < 256; off <<= 1) {
        int add = (t >= off) ? sm[t - off] : 0;
        __syncthreads();
        gs += add;
        sm[t] = gs;
        __syncthreads();
    }
    ebs[t] = gs - gv;
    cnts[t] = gv;
    wdeg[t] = 0.f;
    cnt[t] = 0;
    __syncthreads();

    const int ecnt = cnts[b];
    const int eb   = ebs[b];
    const int2* be = bedge + (size_t)b * CAP;
    if (b == 0 && t == 0) ptr[N] = E;

    for (int p = t; p < ecnt; p += 256) {
        int2 rec = be[p];
        int cl = (rec.x >> 24) & 255;
        atomicAdd(&cnt[cl], 1);
        atomicAdd(&wdeg[cl], __int_as_float(rec.y));   // LDS f32 atomic
    }
    __syncthreads();

    // exclusive scan of per-node counts
    int v = cnt[t];
    int s = v;
    sm[t] = s;
    __syncthreads();
    for (int off = 1; off < 256; off <<= 1) {
        int add = (t >= off) ? sm[t - off] : 0;
        __syncthreads();
        s += add;
        sm[t] = s;
        __syncthreads();
    }
    int excl = s - v;
    cur[t] = excl;
    int n = nb0 + t;
    if (n < N) {
        dis[n] = rsqrtf(1.0f + wdeg[t]);
        ptr[n] = eb + excl;
    }
    __syncthreads();

    for (int p = t; p < ecnt; p += 256) {
        int2 rec = be[p];
        int cl = (rec.x >> 24) & 255;
        int lpos = atomicAdd(&cur[cl], 1);
        int2 o;
        o.x = rec.x & 0xFFFFFF;
        o.y = rec.y;
        sedge[eb + lpos] = o;
    }
}

// ---------- MFMA GEMM: hs(bf16) = (x @ W) * dis ----------
// 64 rows/block, full 128 cols. 4 waves; wave w owns rows [w*16, w*16+16).
// LDS: x tile bf16 [64][128] (converted here, used once), W^T bf16 [128][128]
// copied linearly from pre-swizzled wt. Both XOR-swizzled (ushort idx ^= (row&7)<<3)
// so 16-lane same-column fragment reads spread across banks (T2).
__global__ __launch_bounds__(256) void k_gemm_hs(const float* __restrict__ x,
                                                 const unsigned short* __restrict__ wt,
                                                 const float* __restrict__ dis,
                                                 unsigned short* __restrict__ hsb, int N) {
    __shared__ __align__(16) unsigned short xsb[64 * 128];    // 16 KB
    __shared__ __align__(16) unsigned short wsb[128 * 128];   // 32 KB

    const int t = threadIdx.x;
    const int base = blockIdx.x * 64;

    // stage W^T: linear 16B copies, swizzle already applied in global source
    for (int i = t; i < (128 * 128) / 8; i += 256)
        ((uint4*)wsb)[i] = ((const uint4*)wt)[i];

    // stage x tile: xsb[r][k] = bf16(x[base+r][k]); coalesced float4 reads
    for (int i = t; i < 64 * 32; i += 256) {
        int r = i >> 5;
        int c4 = (i & 31) * 4;
        int gr = base + r;
        if (gr >= N) gr = N - 1;
        float4 v = *(const float4*)&x[(size_t)gr * IN_C + c4];
        ushort4 bv;
        bv.x = (unsigned short)f2bf(v.x);
        bv.y = (unsigned short)f2bf(v.y);
        bv.z = (unsigned short)f2bf(v.z);
        bv.w = (unsigned short)f2bf(v.w);
        int idx = (r * 128 + c4) ^ ((r & 7) << 3);
        *(ushort4*)&xsb[idx] = bv;
    }
    __syncthreads();

    const int w  = t >> 6;
    const int l  = t & 63;
    const int lr = l & 15;            // A row / B col within 16
    const int lk = (l >> 4) * 8;      // k offset within 32

    f32x4 acc[8];
    #pragma unroll
    for (int nt = 0; nt < 8; ++nt) acc[nt] = (f32x4){0.f, 0.f, 0.f, 0.f};

    #pragma unroll
    for (int ks = 0; ks < 4; ++ks) {
        int k0 = ks * 32 + lk;
        int arow = w * 16 + lr;
        bf16x8 a = *(const bf16x8*)&xsb[(arow * 128 + k0) ^ ((arow & 7) << 3)];
        #pragma unroll
        for (int nt = 0; nt < 8; ++nt) {
            int bn = nt * 16 + lr;
            bf16x8 bb = *(const bf16x8*)&wsb[(bn * 128 + k0) ^ ((bn & 7) << 3)];
            acc[nt] = __builtin_amdgcn_mfma_f32_16x16x32_bf16(a, bb, acc[nt], 0, 0, 0);
        }
    }

    // epilogue: D row = (l>>4)*4 + j, col = nt*16 + lr (m89-verified layout)
    const int mbase = base + w * 16 + (l >> 4) * 4;
    float d[4];
    #pragma unroll
    for (int j = 0; j < 4; ++j)
        d[j] = (mbase + j < N) ? dis[mbase + j] : 0.f;
    #pragma unroll
    for (int nt = 0; nt < 8; ++nt) {
        int c = nt * 16 + lr;
        #pragma unroll
        for (int j = 0; j < 4; ++j) {
            int n = mbase + j;
            if (n < N)
                hsb[(size_t)n * HID_C + c] = (unsigned short)f2bf(acc[nt][j] * d[j]);
        }
    }
}

// ---------- pull aggregation: one wave per node, bf16 gather, fp32 accumulate ----------
__global__ __launch_bounds__(256) void k_aggregate(const unsigned int* __restrict__ hsb,
                                                   const int2* __restrict__ sedge,
                                                   const int* __restrict__ ptr,
                                                   const float* __restrict__ dis,
                                                   const float* __restrict__ bias,
                                                   float* __restrict__ out, int N) {
    int t = threadIdx.x;
    int n = blockIdx.x * 4 + (t >> 6);
    if (n >= N) return;
    int lane = t & 63;                 // channels 2*lane, 2*lane+1

    int p   = ptr[n];
    int end = ptr[n + 1];

    unsigned sv = hsb[(size_t)n * (HID_C / 2) + lane];   // self term
    float2 acc = { bf_lo(sv), bf_hi(sv) };

    #pragma unroll 8
    for (; p < end; ++p) {
        int2 e = sedge[p];             // wave-uniform
        float wt = __int_as_float(e.y);
        unsigned v = hsb[(size_t)e.x * (HID_C / 2) + lane];
        acc.x = fmaf(wt, bf_lo(v), acc.x);
        acc.y = fmaf(wt, bf_hi(v), acc.y);
    }

    float d = dis[n];
    float2 bv = ((const float2*)bias)[lane];
    float2 o;
    o.x = fmaxf(fmaf(d, acc.x, bv.x), 0.f);
    o.y = fmaxf(fmaf(d, acc.y, bv.y), 0.f);
    ((float2*)(out + (size_t)n * HID_C))[lane] = o;
}

extern "C" void kernel_launch(void* const* d_in, const int* in_sizes, int n_in,
                              void* d_out, int out_size, void* d_ws, size_t ws_size,
                              hipStream_t stream) {
    const float* x    = (const float*)d_in[0];
    const int*   ei   = (const int*)d_in[1];
    const float* w    = (const float*)d_in[2];
    const float* W    = (const float*)d_in[3];
    const float* bias = (const float*)d_in[4];
    float* out = (float*)d_out;

    const int N = in_sizes[0] / IN_C;
    const int E = in_sizes[2];
    const int* row = ei;        // edge_index[0] (source)
    const int* col = ei + E;    // edge_index[1] (destination)
    const int NBK = (N + 255) >> 8;   // 196 buckets of 256 nodes

    // workspace: gcur[256] | ptr[N+1] | dis[N] | wt[16384] ushort
    //            | bedge[NBK*CAP] int2 | sedge[E] int2 | hsb[N*128] ushort
    auto alup = [](size_t v) { return (v + 255) & ~(size_t)255; };
    char* p = (char*)d_ws;
    int*   gcur  = (int*)p;   p += alup(256 * 4);
    int*   ptr   = (int*)p;   p += alup(((size_t)N + 1) * 4);
    float* dis   = (float*)p; p += alup((size_t)N * 4);
    unsigned short* wt = (unsigned short*)p; p += alup(16384 * 2);
    int2*  bedge = (int2*)p;  p += alup((size_t)NBK * CAP * 8);
    int2*  sedge = (int2*)p;  p += alup((size_t)E * 8);
    unsigned short* hsb = (unsigned short*)p; p += alup((size_t)N * HID_C * 2);

    k_prepW<<<16, 256, 0, stream>>>(W, wt, gcur);

    k_passA<<<(E + EPB - 1) / EPB, 256, 0, stream>>>(row, col, w, gcur, bedge, E, NBK);
    k_passB<<<NBK, 256, 0, stream>>>(bedge, gcur, sedge, ptr, dis, E, N, NBK);

    k_gemm_hs<<<(N + 63) / 64, 256, 0, stream>>>(x, wt, dis, hsb, N);

    k_aggregate<<<(N + 3) / 4, 256, 0, stream>>>((const unsigned int*)hsb, sedge, ptr,
                                                 dis, bias, out, N);
}